// Round 6
// baseline (144.629 us; speedup 1.0000x reference)
//
#include <hip/hip_runtime.h>
#include <cstdint>

#define MARGIN_F 0.2f

typedef __attribute__((ext_vector_type(8))) short sv8;   // 8 x bf16 (4 VGPRs)
typedef __attribute__((ext_vector_type(4))) float fv4;   // MFMA accumulator

// ---- round-to-nearest-even fp32 -> bf16 (bit pattern) ----
__device__ __forceinline__ unsigned short f2bf(float x) {
    unsigned u = __float_as_uint(x);
    unsigned r = (u + 0x7fffu + ((u >> 16) & 1u)) >> 16;
    return (unsigned short)r;
}

// ---- async global->LDS, 16B per lane (dest = wave-uniform base + lane*16) ----
__device__ __forceinline__ void gload16(const void* g, void* l) {
    __builtin_amdgcn_global_load_lds(
        (const __attribute__((address_space(1))) unsigned*)g,
        (__attribute__((address_space(3))) unsigned*)l,
        16, 0, 0);
}

// =====================================================================
// prep: norms, d_pos (fp32 exact) + bf16 conversion of e1,e2
// =====================================================================
__global__ __launch_bounds__(128) void prep_kernel(
    const float* __restrict__ e1, const float* __restrict__ e2,
    unsigned short* __restrict__ e1b, unsigned short* __restrict__ e2b,
    float* __restrict__ n1, float* __restrict__ n2, float* __restrict__ dpos)
{
    const int row = blockIdx.x;
    const int t = threadIdx.x;
    const float4 a = reinterpret_cast<const float4*>(e1 + (size_t)row * 512)[t];
    const float4 b = reinterpret_cast<const float4*>(e2 + (size_t)row * 512)[t];

    ushort4 pa, pb;
    pa.x = f2bf(a.x); pa.y = f2bf(a.y); pa.z = f2bf(a.z); pa.w = f2bf(a.w);
    pb.x = f2bf(b.x); pb.y = f2bf(b.y); pb.z = f2bf(b.z); pb.w = f2bf(b.w);
    reinterpret_cast<ushort4*>(e1b + (size_t)row * 512)[t] = pa;
    reinterpret_cast<ushort4*>(e2b + (size_t)row * 512)[t] = pb;

    float s1 = a.x*a.x + a.y*a.y + a.z*a.z + a.w*a.w;
    float s2 = b.x*b.x + b.y*b.y + b.z*b.z + b.w*b.w;
    float dx = a.x-b.x, dy = a.y-b.y, dz = a.z-b.z, dw = a.w-b.w;
    float sp = dx*dx + dy*dy + dz*dz + dw*dw;

    #pragma unroll
    for (int o = 32; o; o >>= 1) {
        s1 += __shfl_down(s1, o);
        s2 += __shfl_down(s2, o);
        sp += __shfl_down(sp, o);
    }
    __shared__ float r1[2], r2[2], rp[2];
    if ((t & 63) == 0) { int wv = t >> 6; r1[wv] = s1; r2[wv] = s2; rp[wv] = sp; }
    __syncthreads();
    if (t == 0) {
        n1[row] = r1[0] + r1[1];
        n2[row] = r2[0] + r2[1];
        dpos[row] = sqrtf(rp[0] + rp[1]);
    }
}

// =====================================================================
// main: 512 blocks (exactly 2/CU), 512 threads (8 waves as 2x4),
// 256x256 tiles, BK=64, double-buffered counted-vmcnt pipeline.
// XCD-chunked swizzle: logical chunk x -> XCD x (bid%8 round-robin).
// Logical layout per 64-block chunk: 62 "normal" blocks + 2 diag-pair.
//   normals n<256       : G12 (8x8 supertiles, operand set <= 4MB)
//   n in [256,376)      : G11 strict-upper triangle (e1 only)
//   n in [376,496)      : G22 strict-upper triangle (e2 only)
//   diag-pair d in [0,16): G11-diag(d) then G22-diag(d), two passes
// =====================================================================
__global__ __launch_bounds__(512, 2) void triplet_main(
    const unsigned short* __restrict__ e1b, const unsigned short* __restrict__ e2b,
    const float* __restrict__ n1, const float* __restrict__ n2,
    const float* __restrict__ dpos,
    float* __restrict__ total, unsigned* __restrict__ count)
{
    // [0,64K) buf0 (A+B) | [64K,128K) buf1 | 4KB scalars | scratch
    __shared__ char lds[135232];
    float* scRN = (float*)(lds + 131072);   // rowN[256]
    float* scRD = (float*)(lds + 132096);   // rowDP[256]
    float* scCN = (float*)(lds + 133120);   // colN[256]
    float* scCD = (float*)(lds + 134144);   // colDP[256]

    // ---- bijective XCD-chunk swizzle + logical decode ----
    const int bid = blockIdx.x;
    const int L   = ((bid & 7) << 6) | (bid >> 3);   // chunk = XCD
    const int pos = L & 63, chunk = L >> 6;
    int flavor, bi, bj;                              // 0=G12 1=G11 2=G22 3=diagpair
    if (pos >= 62) { flavor = 3; bi = bj = (chunk << 1) + (pos - 62); }
    else {
        const int n = chunk * 62 + pos;              // 0..495
        if (n < 256) {
            flavor = 0;
            const int st = n >> 6, i2 = n & 63;
            bi = ((st >> 1) << 3) + (i2 >> 3);
            bj = ((st & 1) << 3) + (i2 & 7);
        } else {
            int t = n - 256; flavor = 1;
            if (t >= 120) { t -= 120; flavor = 2; }
            int rem = t, rr = 0;
            while (rem >= 15 - rr) { rem -= 15 - rr; ++rr; }
            bi = rr; bj = rr + 1 + rem;
        }
    }
    const int i0 = bi << 8, j0 = bj << 8;

    const int tid  = threadIdx.x;
    const int w    = tid >> 6;
    const int lane = tid & 63;
    const int l15  = lane & 15;
    const int l4   = lane >> 4;
    const int wr   = w >> 2;      // 0..1  (row wave: 128 rows)
    const int wc   = w & 3;       // 0..3  (col wave: 64 cols)

    // ---- staging offsets (pre-swizzled source, linear LDS dest) ----
    int offc[4];
    #pragma unroll
    for (int c = 0; c < 4; ++c) {
        const int chnk = tid + (c << 9);             // 0..2047
        const int row  = chnk >> 3;                  // 0..255
        const int slot = (chnk & 7) << 4;
        offc[c] = row * 1024 + (slot ^ ((row & 7) << 4));
    }
    const int ldst = w << 10;                        // wave-uniform dest part

    // ---- swizzled ds_read bases (row*128 + slot), khalf = ^64 ----
    const int swz = (l15 & 7) << 4;
    const int sl0 = (l4 << 4) ^ swz;
    const int aB  = (wr << 14) + l15 * 128 + sl0;            // A rows wr*128+..
    const int bBn = 32768 + (wc << 13) + l15 * 128 + sl0;    // B rows wc*64+..
    const int bBd = (wc << 13) + l15 * 128 + sl0;            // diag: B == A tile

    fv4 acc[8][4];

#define ZERO_ACC() do {                                                      \
    _Pragma("unroll")                                                        \
    for (int m = 0; m < 8; ++m)                                              \
        _Pragma("unroll")                                                    \
        for (int n = 0; n < 4; ++n) acc[m][n] = (fv4)0.0f;                   \
} while (0)

#define STAGE8(BOFF, T, BI, BJ) do {                                         \
    const long kb_ = (long)(T) << 7;                                         \
    _Pragma("unroll")                                                        \
    for (int c = 0; c < 4; ++c)                                              \
        gload16((BI) + offc[c] + kb_, lds + (BOFF) + (c << 13) + ldst);      \
    _Pragma("unroll")                                                        \
    for (int c = 0; c < 4; ++c)                                              \
        gload16((BJ) + offc[c] + kb_, lds + (BOFF) + 32768 + (c << 13) + ldst); \
} while (0)

#define STAGE4(BOFF, T, BI) do {                                             \
    const long kb_ = (long)(T) << 7;                                         \
    _Pragma("unroll")                                                        \
    for (int c = 0; c < 4; ++c)                                              \
        gload16((BI) + offc[c] + kb_, lds + (BOFF) + (c << 13) + ldst);      \
} while (0)

#define CHALF(BOFF, BBASE, H) do {                                           \
    sv8 a_[8], b_[4];                                                        \
    _Pragma("unroll")                                                        \
    for (int m = 0; m < 8; ++m)                                              \
        a_[m] = *(const sv8*)(lds + (BOFF) + ((aB + m * 2048) ^ (H)));       \
    _Pragma("unroll")                                                        \
    for (int n = 0; n < 4; ++n)                                              \
        b_[n] = *(const sv8*)(lds + (BOFF) + (((BBASE) + n * 2048) ^ (H)));  \
    __builtin_amdgcn_s_setprio(1);                                           \
    _Pragma("unroll")                                                        \
    for (int m = 0; m < 8; ++m)                                              \
        _Pragma("unroll")                                                    \
        for (int n = 0; n < 4; ++n)                                          \
            acc[m][n] = __builtin_amdgcn_mfma_f32_16x16x32_bf16(             \
                a_[m], b_[n], acc[m][n], 0, 0, 0);                           \
    __builtin_amdgcn_s_setprio(0);                                           \
} while (0)

    // epilogue (sqrt-domain): C/D col=lane&15, row=(lane>>4)*4+rr
#define EPILOGUE(EMITCOL, NEEDNEQ) do {                                      \
    float cN_[4], cD_[4], cM_[4];                                            \
    _Pragma("unroll")                                                        \
    for (int n = 0; n < 4; ++n) {                                            \
        const int cl = (wc << 6) + (n << 4) + l15;                           \
        cN_[n] = scCN[cl]; cD_[n] = scCD[cl]; cM_[n] = cD_[n] + MARGIN_F;    \
    }                                                                        \
    _Pragma("unroll")                                                        \
    for (int m = 0; m < 8; ++m) {                                            \
        _Pragma("unroll")                                                    \
        for (int rr = 0; rr < 4; ++rr) {                                     \
            const int rl = (wr << 7) + (m << 4) + (l4 << 2) + rr;            \
            const float rN = scRN[rl], rD = scRD[rl], rM = rD + MARGIN_F;    \
            _Pragma("unroll")                                                \
            for (int n = 0; n < 4; ++n) {                                    \
                const int cl = (wc << 6) + (n << 4) + l15;                   \
                const float s = sqrtf(fmaxf(fmaf(-2.0f, acc[m][n][rr],       \
                                                 rN + cN_[n]), 0.0f));       \
                const bool neq = !(NEEDNEQ) || (rl != cl);                   \
                bool c1 = neq && (rD < s);                                   \
                lcnt += c1; ltot += c1 ? fmaxf(rM - s, 0.0f) : 0.0f;         \
                bool c2 = (EMITCOL) && neq && (cD_[n] < s);                  \
                lcnt += c2; ltot += c2 ? fmaxf(cM_[n] - s, 0.0f) : 0.0f;     \
            }                                                                \
        }                                                                    \
    }                                                                        \
} while (0)

    float    ltot = 0.0f;
    unsigned lcnt = 0;

    if (flavor != 3) {
        const char* Xc = (const char*)((flavor == 2) ? e2b : e1b);
        const char* Yc = (const char*)((flavor == 1) ? e1b : e2b);
        const float* nRp = (flavor == 2) ? n2 : n1;
        const float* nCp = (flavor == 1) ? n1 : n2;
        const bool needNeq = (i0 == j0);             // only possible in G12
        const char* baseI = Xc + (long)i0 * 1024;
        const char* baseJ = Yc + (long)j0 * 1024;

        // scalars first (their waits precede staging issue)
        if (tid < 256)      { scRN[tid] = nRp[i0 + tid]; scRD[tid] = dpos[i0 + tid]; }
        else { const int t = tid - 256; scCN[t] = nCp[j0 + t]; scCD[t] = dpos[j0 + t]; }

        ZERO_ACC();
        // prologue: prefetch tiles 0,1; wait tile 0 only
        STAGE8(0, 0, baseI, baseJ);
        STAGE8(65536, 1, baseI, baseJ);
        asm volatile("s_waitcnt vmcnt(8)" ::: "memory");
        asm volatile("s_barrier" ::: "memory");

        #pragma unroll
        for (int t = 0; t < 8; ++t) {
            const int boff = (t & 1) ? 65536 : 0;
            CHALF(boff, bBn, 0);
            CHALF(boff, bBn, 64);
            if (t == 7) break;
            asm volatile("s_barrier" ::: "memory");
            if (t < 6) {
                STAGE8(boff, t + 2, baseI, baseJ);
                asm volatile("s_waitcnt vmcnt(8)" ::: "memory");
            } else {
                asm volatile("s_waitcnt vmcnt(0)" ::: "memory");
            }
            asm volatile("s_barrier" ::: "memory");
        }
        EPILOGUE(true, needNeq);
    } else {
        // diag-pair: G11-diag(bi) then G22-diag(bi), sequential passes
        #pragma unroll
        for (int g = 0; g < 2; ++g) {
            const char* baseI = (const char*)(g ? e2b : e1b) + (long)i0 * 1024;
            const float* nG = g ? n2 : n1;
            __syncthreads();      // prior pass done reading scalars/LDS
            if (tid < 256)      { scRN[tid] = nG[i0 + tid]; scRD[tid] = dpos[i0 + tid]; }
            else { const int t = tid - 256; scCN[t] = nG[i0 + t]; scCD[t] = dpos[i0 + t]; }
            ZERO_ACC();
            for (int t = 0; t < 8; ++t) {
                STAGE4(0, t, baseI);
                __syncthreads();
                CHALF(0, bBd, 0);
                CHALF(0, bBd, 64);
                __syncthreads();
            }
            EPILOGUE(false, true);
        }
    }

    // ---- block reduction: wave shuffle -> LDS -> one atomic pair ----
    #pragma unroll
    for (int o = 32; o; o >>= 1) {
        ltot += __shfl_down(ltot, o);
        lcnt += __shfl_down(lcnt, o);
    }
    float*    lt = (float*)(lds + 135168);
    unsigned* lc = (unsigned*)(lds + 135168 + 32);
    __syncthreads();              // all epilogue LDS reads done
    if (lane == 0) { lt[w] = ltot; lc[w] = lcnt; }
    __syncthreads();
    if (tid == 0) {
        float T = 0.0f; unsigned C = 0;
        #pragma unroll
        for (int x = 0; x < 8; ++x) { T += lt[x]; C += lc[x]; }
        atomicAdd(total, T);
        atomicAdd(count, C);
    }
#undef ZERO_ACC
#undef STAGE8
#undef STAGE4
#undef CHALF
#undef EPILOGUE
}

__global__ void finalize_kernel(const float* __restrict__ total,
                                const unsigned* __restrict__ count,
                                float* __restrict__ out)
{
    out[0] = total[0] / fmaxf((float)count[0], 1.0f);
}

// =====================================================================
// Workspace layout (~8.6 MB):
//   [0,8)        : total (f32), count (u32)
//   [1024, ...)  : n1[4096], n2[4096], dpos[4096]  (f32)
//   [131072, ..) : e1b 4096x512 bf16 (4MB), then e2b (4MB)
// =====================================================================
extern "C" void kernel_launch(void* const* d_in, const int* in_sizes, int n_in,
                              void* d_out, int out_size, void* d_ws, size_t ws_size,
                              hipStream_t stream) {
    const float* e1 = (const float*)d_in[0];
    const float* e2 = (const float*)d_in[1];
    char* ws = (char*)d_ws;

    float*    total = (float*)ws;
    unsigned* count = (unsigned*)(ws + 4);
    float* n1   = (float*)(ws + 1024);
    float* n2   = n1 + 4096;
    float* dpos = n2 + 4096;
    unsigned short* e1b = (unsigned short*)(ws + (1 << 17));
    unsigned short* e2b = e1b + (size_t)4096 * 512;

    hipMemsetAsync(ws, 0, 64, stream);
    prep_kernel<<<4096, 128, 0, stream>>>(e1, e2, e1b, e2b, n1, n2, dpos);
    triplet_main<<<512, 512, 0, stream>>>(e1b, e2b, n1, n2, dpos, total, count);
    finalize_kernel<<<1, 1, 0, stream>>>(total, count, (float*)d_out);
}